// Round 3
// baseline (231.411 us; speedup 1.0000x reference)
//
#include <hip/hip_runtime.h>

// Separable 3D Gaussian blur (sigma=1, truncate=3 -> 7 taps), SAME zero padding.
// (N=2, D=160, H=160, W=160, C=4) float32 == float4 over C.
// Fused single pass: 16x16 (H,W) tile streamed along D with a 7-slice register
// ring. Per slice: stage 22x22 halo in LDS, W-blur to LDS, H-blur to ring.
// KEY CHANGE vs prev round: register prefetch of the next slice + raw
// s_barrier with lgkmcnt-only waits (no vmcnt(0) drain) so global loads stay
// in flight across barriers -> HBM latency hidden under blur compute.

#define TILE 16
#define CHUNK 16           // output D-slices per block -> 2000 blocks
#define DIM 160
#define SLICE (DIM * DIM)  // float4 elements per (D) slice

#define W0 0.004433048f
#define W1 0.054005582f
#define W2 0.242036229f
#define W3 0.399050300f

__device__ __forceinline__ float4 blur7(float4 a0, float4 a1, float4 a2, float4 a3,
                                        float4 a4, float4 a5, float4 a6) {
    float4 r;
    r.x = W0 * (a0.x + a6.x) + W1 * (a1.x + a5.x) + W2 * (a2.x + a4.x) + W3 * a3.x;
    r.y = W0 * (a0.y + a6.y) + W1 * (a1.y + a5.y) + W2 * (a2.y + a4.y) + W3 * a3.y;
    r.z = W0 * (a0.z + a6.z) + W1 * (a1.z + a5.z) + W2 * (a2.z + a4.z) + W3 * a3.z;
    r.w = W0 * (a0.w + a6.w) + W1 * (a1.w + a5.w) + W2 * (a2.w + a4.w) + W3 * a3.w;
    return r;
}

// LDS-visibility barrier WITHOUT the vmcnt(0) drain __syncthreads() emits.
// Pattern verified by the 8-phase GEMM template (learn_hip m194-m201).
__device__ __forceinline__ void lds_barrier() {
    asm volatile("s_waitcnt lgkmcnt(0)" ::: "memory");
    __builtin_amdgcn_s_barrier();
    __builtin_amdgcn_sched_barrier(0);
}

__global__ __launch_bounds__(256, 8)
void gauss3d_fused(const float4* __restrict__ in, float4* __restrict__ out) {
    // decode block: (tw, th, chunk, n)
    int bid = blockIdx.x;
    const int tw    = bid % (DIM / TILE);  bid /= (DIM / TILE);
    const int th    = bid % (DIM / TILE);  bid /= (DIM / TILE);
    const int chunk = bid % (DIM / CHUNK); bid /= (DIM / CHUNK);
    const int n     = bid;

    const int h0 = th * TILE;
    const int w0 = tw * TILE;
    const int d0 = chunk * CHUNK;

    __shared__ float4 raw[22][23];  // halo tile, +1 pad
    __shared__ float4 wb[22][17];   // W-blurred, +1 pad

    const int tid = threadIdx.x;
    const int lh = tid >> 4;       // 0..15
    const int lw = tid & 15;       // 0..15

    const size_t nbase = (size_t)n * DIM * SLICE;
    const float4 z = make_float4(0.f, 0.f, 0.f, 0.f);

    // --- per-thread constants for the 22x22 stage (2 elements/thread) ---
    const int iA = tid;            // 0..255
    const int iB = tid + 256;      // 256..511 (valid < 484)
    const int rA = iA / 22, cA = iA % 22;
    const int rB = iB / 22, cB = iB % 22;
    const bool hasB = (iB < 22 * 22);
    const int ghA = h0 + rA - 3, gwA = w0 + cA - 3;
    const int ghB = h0 + rB - 3, gwB = w0 + cB - 3;
    const bool okA = (ghA >= 0 && ghA < DIM && gwA >= 0 && gwA < DIM);
    const bool okB = hasB && (ghB >= 0 && ghB < DIM && gwB >= 0 && gwB < DIM);
    const int offA = okA ? (ghA * DIM + gwA) : 0;
    const int offB = okB ? (ghB * DIM + gwB) : 0;

    // --- per-thread constants for the W-blur stage (22x16 = 352 outputs) ---
    const int wrA = tid >> 4, wcA = tid & 15;          // rows 0..15
    const int wrB = 16 + (tid >> 4), wcB = tid & 15;   // rows 16..21 (tid<96)
    const bool hasW = (tid < 96);

    float4 pfA, pfB;
    float4 r0 = z, r1 = z, r2 = z, r3 = z, r4 = z, r5 = z, r6 = z;

#define PREFETCH(DSL)                                                        \
    do {                                                                     \
        const int _d = (DSL);                                                \
        const bool _inr = (_d >= 0) && (_d < DIM);                           \
        const float4* _s = in + nbase + (size_t)(_inr ? _d : 0) * SLICE;     \
        pfA = (_inr && okA) ? _s[offA] : z;                                  \
        pfB = (_inr && okB) ? _s[offB] : z;                                  \
    } while (0)

    PREFETCH(d0 - 3);

    for (int din = d0 - 3; din <= d0 + CHUNK + 2; ++din) {
        // 1) commit prefetched slice to LDS (hazard vs prev wblur reads
        //    covered by barrier B of previous iteration)
        raw[rA][cA] = pfA;
        if (hasB) raw[rB][cB] = pfB;

        // 2) issue next slice's loads now; latency hides under blur compute.
        PREFETCH(din + 1);

        lds_barrier();  // A: raw visible; prev hblur done reading wb

        // 3) W-blur: 22 rows x 16 cols
        wb[wrA][wcA] = blur7(raw[wrA][wcA], raw[wrA][wcA + 1], raw[wrA][wcA + 2],
                             raw[wrA][wcA + 3], raw[wrA][wcA + 4], raw[wrA][wcA + 5],
                             raw[wrA][wcA + 6]);
        if (hasW)
            wb[wrB][wcB] = blur7(raw[wrB][wcB], raw[wrB][wcB + 1], raw[wrB][wcB + 2],
                                 raw[wrB][wcB + 3], raw[wrB][wcB + 4], raw[wrB][wcB + 5],
                                 raw[wrB][wcB + 6]);

        lds_barrier();  // B: wb visible; raw reads done (next iter may overwrite)

        // 4) H-blur at (lh, lw) -> register ring
        float4 v = blur7(wb[lh][lw], wb[lh + 1][lw], wb[lh + 2][lw], wb[lh + 3][lw],
                         wb[lh + 4][lw], wb[lh + 5][lw], wb[lh + 6][lw]);
        r0 = r1; r1 = r2; r2 = r3; r3 = r4; r4 = r5; r5 = r6; r6 = v;

        const int dout = din - 3;
        if (dout >= d0 && dout < d0 + CHUNK) {
            float4 o = blur7(r0, r1, r2, r3, r4, r5, r6);
            out[nbase + ((size_t)dout * DIM + (h0 + lh)) * DIM + (w0 + lw)] = o;
        }
    }
#undef PREFETCH
}

extern "C" void kernel_launch(void* const* d_in, const int* in_sizes, int n_in,
                              void* d_out, int out_size, void* d_ws, size_t ws_size,
                              hipStream_t stream) {
    const float4* in = (const float4*)d_in[0];
    float4* out = (float4*)d_out;
    const int nblocks = 2 * (DIM / TILE) * (DIM / TILE) * (DIM / CHUNK); // 2000
    gauss3d_fused<<<nblocks, 256, 0, stream>>>(in, out);
}

// Round 4
// 110.555 us; speedup vs baseline: 2.0932x; 2.0932x over previous
//
#include <hip/hip_runtime.h>

// Separable 3D Gaussian blur (sigma=1, truncate=3 -> 7 taps), SAME zero padding.
// (N=2, D=160, H=160, W=160, C=4) float32 == float4 over C.
// Fused single pass: 16x16 (H,W) tile streamed along D with a 7-slice register
// ring. Per slice: stage 22x22 halo in LDS (double-buffered), W-blur to shared
// LDS, H-blur to ring.
// Latency hiding: next slice prefetched into registers right after committing
// the current one; barriers are lgkmcnt-only (no vmcnt drain) so those global
// loads stay in flight across the whole compute phase.
// vs round 3: NO sched_barrier(0) (it pinned scheduling and forced scratch
// spills -> +530MB HBM traffic), launch_bounds min-waves 8->6 (VGPR cap 64->85
// so the 28-reg ring + 8-reg prefetch fit without spilling).

#define TILE 16
#define CHUNK 16           // output D-slices per block -> 2000 blocks
#define DIM 160
#define SLICE (DIM * DIM)  // float4 elements per (D) slice

#define W0 0.004433048f
#define W1 0.054005582f
#define W2 0.242036229f
#define W3 0.399050300f

__device__ __forceinline__ float4 blur7(float4 a0, float4 a1, float4 a2, float4 a3,
                                        float4 a4, float4 a5, float4 a6) {
    float4 r;
    r.x = W0 * (a0.x + a6.x) + W1 * (a1.x + a5.x) + W2 * (a2.x + a4.x) + W3 * a3.x;
    r.y = W0 * (a0.y + a6.y) + W1 * (a1.y + a5.y) + W2 * (a2.y + a4.y) + W3 * a3.y;
    r.z = W0 * (a0.z + a6.z) + W1 * (a1.z + a5.z) + W2 * (a2.z + a4.z) + W3 * a3.z;
    r.w = W0 * (a0.w + a6.w) + W1 * (a1.w + a5.w) + W2 * (a2.w + a4.w) + W3 * a3.w;
    return r;
}

// LDS-visibility barrier WITHOUT the vmcnt(0) drain __syncthreads() emits.
// "memory" clobber keeps compiler-emitted LDS ops ordered around it; global
// loads (vmcnt) are free to stay in flight.
__device__ __forceinline__ void lds_barrier() {
    asm volatile("s_waitcnt lgkmcnt(0)" ::: "memory");
    __builtin_amdgcn_s_barrier();
}

__global__ __launch_bounds__(256, 6)
void gauss3d_fused(const float4* __restrict__ in, float4* __restrict__ out) {
    // decode block: (tw, th, chunk, n)
    int bid = blockIdx.x;
    const int tw    = bid % (DIM / TILE);  bid /= (DIM / TILE);
    const int th    = bid % (DIM / TILE);  bid /= (DIM / TILE);
    const int chunk = bid % (DIM / CHUNK); bid /= (DIM / CHUNK);
    const int n     = bid;

    const int h0 = th * TILE;
    const int w0 = tw * TILE;
    const int d0 = chunk * CHUNK;

    __shared__ float4 raw[2][22][23];  // double-buffered halo tile, +1 pad
    __shared__ float4 wb[22][17];      // W-blurred, +1 pad (shared, single)

    const int tid = threadIdx.x;
    const int lh = tid >> 4;       // 0..15
    const int lw = tid & 15;       // 0..15

    const size_t nbase = (size_t)n * DIM * SLICE;
    const float4 z = make_float4(0.f, 0.f, 0.f, 0.f);

    // --- per-thread constants for the 22x22 stage (2 elements/thread) ---
    const int iA = tid;            // 0..255
    const int iB = tid + 256;      // 256..511 (valid < 484)
    const int rA = iA / 22, cA = iA % 22;
    const int rB = iB / 22, cB = iB % 22;
    const bool hasB = (iB < 22 * 22);
    const int ghA = h0 + rA - 3, gwA = w0 + cA - 3;
    const int ghB = h0 + rB - 3, gwB = w0 + cB - 3;
    const bool okA = (ghA >= 0 && ghA < DIM && gwA >= 0 && gwA < DIM);
    const bool okB = hasB && (ghB >= 0 && ghB < DIM && gwB >= 0 && gwB < DIM);
    const int offA = okA ? (ghA * DIM + gwA) : 0;
    const int offB = okB ? (ghB * DIM + gwB) : 0;

    // --- per-thread constants for the W-blur stage (22x16 = 352 outputs) ---
    const int wrA = tid >> 4, wcA = tid & 15;          // rows 0..15
    const int wrB = 16 + (tid >> 4), wcB = tid & 15;   // rows 16..21 (tid<96)
    const bool hasW = (tid < 96);

    float4 pfA, pfB;
    float4 r0 = z, r1 = z, r2 = z, r3 = z, r4 = z, r5 = z, r6 = z;

#define PREFETCH(DSL)                                                        \
    do {                                                                     \
        const int _d = (DSL);                                                \
        const bool _inr = (_d >= 0) && (_d < DIM);                           \
        const float4* _s = in + nbase + (size_t)(_inr ? _d : 0) * SLICE;     \
        pfA = (_inr && okA) ? _s[offA] : z;                                  \
        pfB = (_inr && okB) ? _s[offB] : z;                                  \
    } while (0)

    PREFETCH(d0 - 3);
    int buf = 0;

    for (int din = d0 - 3; din <= d0 + CHUNK + 2; ++din) {
        // 1) commit prefetched slice din to LDS buffer `buf`
        //    (other buffer was read 2 iters ago -> no hazard)
        raw[buf][rA][cA] = pfA;
        if (hasB) raw[buf][rB][cB] = pfB;

        // 2) issue next slice's loads; they stay in flight across both
        //    lgkmcnt-only barriers and the blur compute below.
        PREFETCH(din + 1);

        lds_barrier();  // A: raw[buf] visible; prev iter's wb reads drained

        // 3) W-blur: 22 rows x 16 cols from raw[buf]
        wb[wrA][wcA] = blur7(raw[buf][wrA][wcA],     raw[buf][wrA][wcA + 1],
                             raw[buf][wrA][wcA + 2], raw[buf][wrA][wcA + 3],
                             raw[buf][wrA][wcA + 4], raw[buf][wrA][wcA + 5],
                             raw[buf][wrA][wcA + 6]);
        if (hasW)
            wb[wrB][wcB] = blur7(raw[buf][wrB][wcB],     raw[buf][wrB][wcB + 1],
                                 raw[buf][wrB][wcB + 2], raw[buf][wrB][wcB + 3],
                                 raw[buf][wrB][wcB + 4], raw[buf][wrB][wcB + 5],
                                 raw[buf][wrB][wcB + 6]);

        lds_barrier();  // B: wb visible

        // 4) H-blur at (lh, lw) -> register ring
        float4 v = blur7(wb[lh][lw], wb[lh + 1][lw], wb[lh + 2][lw], wb[lh + 3][lw],
                         wb[lh + 4][lw], wb[lh + 5][lw], wb[lh + 6][lw]);
        r0 = r1; r1 = r2; r2 = r3; r3 = r4; r4 = r5; r5 = r6; r6 = v;

        const int dout = din - 3;
        if (dout >= d0 && dout < d0 + CHUNK) {
            float4 o = blur7(r0, r1, r2, r3, r4, r5, r6);
            out[nbase + ((size_t)dout * DIM + (h0 + lh)) * DIM + (w0 + lw)] = o;
        }
        buf ^= 1;
    }
#undef PREFETCH
}

extern "C" void kernel_launch(void* const* d_in, const int* in_sizes, int n_in,
                              void* d_out, int out_size, void* d_ws, size_t ws_size,
                              hipStream_t stream) {
    const float4* in = (const float4*)d_in[0];
    float4* out = (float4*)d_out;
    const int nblocks = 2 * (DIM / TILE) * (DIM / TILE) * (DIM / CHUNK); // 2000
    gauss3d_fused<<<nblocks, 256, 0, stream>>>(in, out);
}